// Round 8
// baseline (139.372 us; speedup 1.0000x reference)
//
#include <hip/hip_runtime.h>
#include <hip/hip_bf16.h>

typedef __attribute__((ext_vector_type(8))) short bf16x8;
typedef __attribute__((ext_vector_type(4))) float f32x4;

__device__ __forceinline__ unsigned short f2bf(float f) {
  unsigned int u = __builtin_bit_cast(unsigned int, f);
  u += 0x7fffu + ((u >> 16) & 1u);
  return (unsigned short)(u >> 16);
}

__device__ __forceinline__ f32x4 mfma16(bf16x8 a, bf16x8 b, f32x4 c) {
  return __builtin_amdgcn_mfma_f32_16x16x32_bf16(a, b, c, 0, 0, 0);
}

// ---------------- K0: weight prep (per-row LDS staging) ----------------
// Folds the 3x3 VALID conv into W1:  h@W1^T == x@(W1*C)^T:
//   w1p[o, 28u+v] = sum_{a,b: 0<=u-a<26, 0<=v-b<26} cw[a,b]*w1[o, 26*(u-a)+(v-b)]
// ws layout (unsigned short elems):
//   w1p [256][800] (cols 784..799 zero), w2b [128][256], w3b [64][128],
//   w4b [16][64] (rows 10..15 zero)
__global__ __launch_bounds__(256) void prep_weights(
    const float* __restrict__ w1, const float* __restrict__ w2,
    const float* __restrict__ w3, const float* __restrict__ w4,
    const float* __restrict__ cw,
    unsigned short* __restrict__ w1p, unsigned short* __restrict__ w2b,
    unsigned short* __restrict__ w3b, unsigned short* __restrict__ w4b) {
  __shared__ float wrow[676];
  __shared__ float cws[9];
  const int o = blockIdx.x;
  const int t = threadIdx.x;
  if (t < 9) cws[t] = cw[t];
  for (int i = t; i < 676; i += 256) wrow[i] = w1[o * 676 + i];
  __syncthreads();
#pragma unroll
  for (int it = 0; it < 4; ++it) {
    int p = t + it * 256;
    if (p < 800) {
      float acc = 0.f;
      if (p < 784) {
        int u = p / 28, v = p - u * 28;
#pragma unroll
        for (int a = 0; a < 3; ++a) {
          int ii = u - a;
          if (ii < 0 || ii >= 26) continue;
#pragma unroll
          for (int b = 0; b < 3; ++b) {
            int jj = v - b;
            if (jj < 0 || jj >= 26) continue;
            acc += cws[a * 3 + b] * wrow[26 * ii + jj];
          }
        }
      }
      w1p[o * 800 + p] = f2bf(acc);
    }
  }
  const int idx = o * 256 + t;
  const int stride = 256 * 256;
  for (int i = idx; i < 128 * 256; i += stride) w2b[i] = f2bf(w2[i]);
  for (int i = idx; i < 64 * 128; i += stride) w3b[i] = f2bf(w3[i]);
  for (int i = idx; i < 16 * 64; i += stride) {
    int oo = i >> 6, k = i & 63;
    w4b[i] = f2bf(oo < 10 ? w4[oo * 64 + k] : 0.f);
  }
}

// ---------------- K1: fused (cast x) + 4-layer MLP ----------------
// BM=16 rows, 256 threads (4 waves), grid 1024 -> 4+ blocks/CU,
// __launch_bounds__(256,6): up to 6 blocks/CU (24 waves/CU), VGPR<=85.
// Wave w owns GEMM1 cols w*64..+63 (acc[4]); depth-2 B prefetch hoisted
// above the x-cast phase. Weights direct from global (L2/XCD-resident).
// LDS 25,856 B (shorts), regions overlay:
//   xs  [16][808] @0      (stride 808 -> <=2-way banks, rows 16B-aligned)
//   h1s [16][264] @0      (overlays xs after GEMM1)
//   h2s [16][136] @4352
//   h3s [16][72]  @6656
__global__ __launch_bounds__(256, 6) void fused_mlp(
    const float* __restrict__ x,             // [16384][784]
    const unsigned short* __restrict__ w1p,  // [256][800]
    const unsigned short* __restrict__ w2b,  // [128][256]
    const unsigned short* __restrict__ w3b,  // [64][128]
    const unsigned short* __restrict__ w4b,  // [16][64]
    const float* __restrict__ b1, const float* __restrict__ b2,
    const float* __restrict__ b3, const float* __restrict__ b4,
    float* __restrict__ out)                 // [16384][10]
{
  __shared__ unsigned short lds_s[12928];
  unsigned short* xs  = lds_s;            // stride 808
  unsigned short* h1s = lds_s;            // stride 264
  unsigned short* h2s = lds_s + 4352;     // stride 136
  unsigned short* h3s = lds_s + 6656;     // stride 72

  const int tid = threadIdx.x;
  const int lane = tid & 63;
  const int lane15 = lane & 15;
  const int kg = (lane >> 4) << 3;        // k sub-offset in shorts (0,8,16,24)
  const int w = tid >> 6;                 // wave 0..3
  const int row0 = blockIdx.x * 16;
  const int rb = (lane >> 4) << 2;        // C/D row base within 16x16 tile

  // ---- hoisted GEMM1 B prefetch (depth 2 x 4 col-tiles), independent of xs ----
  const unsigned short* bp = w1p + (w * 64 + lane15) * 800 + kg;
  bf16x8 bA0 = *(const bf16x8*)(bp);
  bf16x8 bA1 = *(const bf16x8*)(bp + 16 * 800);
  bf16x8 bA2 = *(const bf16x8*)(bp + 32 * 800);
  bf16x8 bA3 = *(const bf16x8*)(bp + 48 * 800);
  bf16x8 bB0 = *(const bf16x8*)(bp + 32);
  bf16x8 bB1 = *(const bf16x8*)(bp + 16 * 800 + 32);
  bf16x8 bB2 = *(const bf16x8*)(bp + 32 * 800 + 32);
  bf16x8 bB3 = *(const bf16x8*)(bp + 48 * 800 + 32);

  // ---- Phase 0: x fp32 -> bf16 into xs [16][808] ----
  {
    const float* xblk = x + (size_t)row0 * 784;
    for (int f = tid; f < 16 * 196; f += 256) {
      int rr = f / 196, c4 = f - rr * 196;
      float4 v = *(const float4*)(xblk + rr * 784 + (c4 << 2));
      unsigned int p0 = (unsigned)f2bf(v.x) | ((unsigned)f2bf(v.y) << 16);
      unsigned int p1 = (unsigned)f2bf(v.z) | ((unsigned)f2bf(v.w) << 16);
      unsigned int* dst = (unsigned int*)(xs + rr * 808 + (c4 << 2));
      dst[0] = p0;
      dst[1] = p1;
    }
    if (tid < 128) {  // zero-pad k = 784..799 (8 uints per row)
      int rr = tid >> 3, u = tid & 7;
      *(unsigned int*)(xs + rr * 808 + 784 + (u << 1)) = 0u;
    }
  }
  __syncthreads();

  // ---- GEMM1: [16][800] x w1p^T -> [16][256]; wave w cols w*64..+63 ----
  f32x4 acc1[4] = {};
  {
    const unsigned short* a0p = xs + lane15 * 808 + kg;
#pragma unroll
    for (int ks = 0; ks < 25; ++ks) {
      bf16x8 u0 = bA0, u1 = bA1, u2 = bA2, u3 = bA3;
      bA0 = bB0; bA1 = bB1; bA2 = bB2; bA3 = bB3;
      if (ks + 2 < 25) {
        const unsigned short* p = bp + (ks + 2) * 32;
        bB0 = *(const bf16x8*)(p);
        bB1 = *(const bf16x8*)(p + 16 * 800);
        bB2 = *(const bf16x8*)(p + 32 * 800);
        bB3 = *(const bf16x8*)(p + 48 * 800);
      }
      bf16x8 a0 = *(const bf16x8*)(a0p + ks * 32);
      acc1[0] = mfma16(a0, u0, acc1[0]);
      acc1[1] = mfma16(a0, u1, acc1[1]);
      acc1[2] = mfma16(a0, u2, acc1[2]);
      acc1[3] = mfma16(a0, u3, acc1[3]);
    }
  }
  __syncthreads();  // all xs reads done before h1s overlays it

  // ---- epilogue1: +b1, relu -> h1s [16][264] ----
#pragma unroll
  for (int n = 0; n < 4; ++n) {
    const int col = w * 64 + n * 16 + lane15;
    const float bias = b1[col];
#pragma unroll
    for (int r = 0; r < 4; ++r) {
      float v = acc1[n][r] + bias;
      v = v > 0.f ? v : 0.f;
      h1s[(rb + r) * 264 + col] = f2bf(v);
    }
  }
  __syncthreads();

  // ---- GEMM2: [16][256] x w2^T -> [16][128]; wave w cols w*32..+31 ----
  f32x4 acc2[2] = {};
  {
    const unsigned short* a0p = h1s + lane15 * 264 + kg;
    const unsigned short* bp2 = w2b + (w * 32 + lane15) * 256 + kg;
#pragma unroll
    for (int ks = 0; ks < 8; ++ks) {
      const int k0 = ks << 5;
      bf16x8 a0 = *(const bf16x8*)(a0p + k0);
      bf16x8 f0 = *(const bf16x8*)(bp2 + k0);
      bf16x8 f1 = *(const bf16x8*)(bp2 + 16 * 256 + k0);
      acc2[0] = mfma16(a0, f0, acc2[0]);
      acc2[1] = mfma16(a0, f1, acc2[1]);
    }
  }
  // epilogue2 -> h2s (disjoint region)
#pragma unroll
  for (int n = 0; n < 2; ++n) {
    const int col = w * 32 + n * 16 + lane15;
    const float bias = b2[col];
#pragma unroll
    for (int r = 0; r < 4; ++r) {
      float v = acc2[n][r] + bias;
      v = v > 0.f ? v : 0.f;
      h2s[(rb + r) * 136 + col] = f2bf(v);
    }
  }
  __syncthreads();

  // ---- GEMM3: [16][128] x w3^T -> [16][64]; wave w cols w*16..+15 ----
  f32x4 acc3 = {};
  {
    const unsigned short* a0p = h2s + lane15 * 136 + kg;
    const unsigned short* bp3 = w3b + (w * 16 + lane15) * 128 + kg;
#pragma unroll
    for (int ks = 0; ks < 4; ++ks) {
      const int k0 = ks << 5;
      bf16x8 a0 = *(const bf16x8*)(a0p + k0);
      bf16x8 f0 = *(const bf16x8*)(bp3 + k0);
      acc3 = mfma16(a0, f0, acc3);
    }
    const int col = w * 16 + lane15;
    const float bias = b3[col];
#pragma unroll
    for (int r = 0; r < 4; ++r) {
      float v = acc3[r] + bias;
      v = v > 0.f ? v : 0.f;
      h3s[(rb + r) * 72 + col] = f2bf(v);
    }
  }
  __syncthreads();

  // ---- GEMM4: [16][64] x w4^T -> [16][10]; wave 0 only ----
  if (w == 0) {
    f32x4 acc4 = {};
    const unsigned short* ap = h3s + lane15 * 72 + kg;
    const unsigned short* bp4 = w4b + lane15 * 64 + kg;
#pragma unroll
    for (int ks = 0; ks < 2; ++ks) {
      const int k0 = ks << 5;
      bf16x8 a0 = *(const bf16x8*)(ap + k0);
      bf16x8 f0 = *(const bf16x8*)(bp4 + k0);
      acc4 = mfma16(a0, f0, acc4);
    }
    const int col = lane15;
    if (col < 10) {
      const float bias = b4[col];
#pragma unroll
      for (int r = 0; r < 4; ++r) {
        out[(size_t)(row0 + rb + r) * 10 + col] = acc4[r] + bias;
      }
    }
  }
}

extern "C" void kernel_launch(void* const* d_in, const int* in_sizes, int n_in,
                              void* d_out, int out_size, void* d_ws, size_t ws_size,
                              hipStream_t stream) {
  const float* x  = (const float*)d_in[0];
  const float* cw = (const float*)d_in[1];
  const float* w1 = (const float*)d_in[2];
  const float* b1 = (const float*)d_in[3];
  const float* w2 = (const float*)d_in[4];
  const float* b2 = (const float*)d_in[5];
  const float* w3 = (const float*)d_in[6];
  const float* b3 = (const float*)d_in[7];
  const float* w4 = (const float*)d_in[8];
  const float* b4 = (const float*)d_in[9];
  float* out = (float*)d_out;

  unsigned short* w1p = (unsigned short*)d_ws;          // 256*800
  unsigned short* w2b = w1p + 256 * 800;                // 128*256
  unsigned short* w3b = w2b + 128 * 256;                // 64*128
  unsigned short* w4b = w3b + 64 * 128;                 // 16*64

  hipLaunchKernelGGL(prep_weights, dim3(256), dim3(256), 0, stream,
                     w1, w2, w3, w4, cw, w1p, w2b, w3b, w4b);

  hipLaunchKernelGGL(fused_mlp, dim3(1024), dim3(256), 0, stream,
                     x, w1p, w2b, w3b, w4b, b1, b2, b3, b4, out);
}

// Round 9
// 121.159 us; speedup vs baseline: 1.1503x; 1.1503x over previous
//
#include <hip/hip_runtime.h>
#include <hip/hip_bf16.h>

typedef __attribute__((ext_vector_type(8))) short bf16x8;
typedef __attribute__((ext_vector_type(4))) float f32x4;

__device__ __forceinline__ unsigned short f2bf(float f) {
  unsigned int u = __builtin_bit_cast(unsigned int, f);
  u += 0x7fffu + ((u >> 16) & 1u);
  return (unsigned short)(u >> 16);
}

__device__ __forceinline__ f32x4 mfma16(bf16x8 a, bf16x8 b, f32x4 c) {
  return __builtin_amdgcn_mfma_f32_16x16x32_bf16(a, b, c, 0, 0, 0);
}

// ---------------- K0: weight prep (per-row LDS staging) ----------------
// Folds the 3x3 VALID conv into W1:  h@W1^T == x@(W1*C)^T:
//   w1p[o, 28u+v] = sum_{a,b: 0<=u-a<26, 0<=v-b<26} cw[a,b]*w1[o, 26*(u-a)+(v-b)]
// ws layout (unsigned short elems):
//   w1p [256][800] (cols 784..799 zero), w2b [128][256], w3b [64][128],
//   w4b [16][64] (rows 10..15 zero)
__global__ __launch_bounds__(256) void prep_weights(
    const float* __restrict__ w1, const float* __restrict__ w2,
    const float* __restrict__ w3, const float* __restrict__ w4,
    const float* __restrict__ cw,
    unsigned short* __restrict__ w1p, unsigned short* __restrict__ w2b,
    unsigned short* __restrict__ w3b, unsigned short* __restrict__ w4b) {
  __shared__ float wrow[676];
  __shared__ float cws[9];
  const int o = blockIdx.x;
  const int t = threadIdx.x;
  if (t < 9) cws[t] = cw[t];
  for (int i = t; i < 676; i += 256) wrow[i] = w1[o * 676 + i];
  __syncthreads();
#pragma unroll
  for (int it = 0; it < 4; ++it) {
    int p = t + it * 256;
    if (p < 800) {
      float acc = 0.f;
      if (p < 784) {
        int u = p / 28, v = p - u * 28;
#pragma unroll
        for (int a = 0; a < 3; ++a) {
          int ii = u - a;
          if (ii < 0 || ii >= 26) continue;
#pragma unroll
          for (int b = 0; b < 3; ++b) {
            int jj = v - b;
            if (jj < 0 || jj >= 26) continue;
            acc += cws[a * 3 + b] * wrow[26 * ii + jj];
          }
        }
      }
      w1p[o * 800 + p] = f2bf(acc);
    }
  }
  const int idx = o * 256 + t;
  const int stride = 256 * 256;
  for (int i = idx; i < 128 * 256; i += stride) w2b[i] = f2bf(w2[i]);
  for (int i = idx; i < 64 * 128; i += stride) w3b[i] = f2bf(w3[i]);
  for (int i = idx; i < 16 * 64; i += stride) {
    int oo = i >> 6, k = i & 63;
    w4b[i] = f2bf(oo < 10 ? w4[oo * 64 + k] : 0.f);
  }
}

// ---------------- K1: fused (cast x) + 4-layer MLP ----------------
// R5 geometry (best measured): 512 threads (8 waves), BM=32, grid 512
// (2 blocks/CU, 16 waves/CU). NEW in R9: cross-layer register prefetch —
// GEMM2's full B (8 frags) loaded at kernel top; GEMM3's B during
// epilogue1; GEMM4's B during epilogue2. Kills the per-step L2 dependency
// chains of layers 2-4; GEMM1 keeps the proven depth-3 rotation.
// LDS (static 51,712 B; regions overlay):
//   xs  [32][808]  (stride 808 -> <=2-way banks, rows 16B-aligned)
//   h1s [32][264] @0 (overlays xs)   h2s [32][136] @12800   h3s [32][72] @20480
__global__ __launch_bounds__(512, 4) void fused_mlp(
    const float* __restrict__ x,             // [16384][784]
    const unsigned short* __restrict__ w1p,  // [256][800]
    const unsigned short* __restrict__ w2b,  // [128][256]
    const unsigned short* __restrict__ w3b,  // [64][128]
    const unsigned short* __restrict__ w4b,  // [16][64]
    const float* __restrict__ b1, const float* __restrict__ b2,
    const float* __restrict__ b3, const float* __restrict__ b4,
    float* __restrict__ out)                 // [16384][10]
{
  __shared__ unsigned short lds_s[25856];
  unsigned short* xs  = lds_s;            // stride 808
  unsigned short* h1s = lds_s;            // stride 264
  unsigned short* h2s = lds_s + 12800;    // stride 136
  unsigned short* h3s = lds_s + 20480;    // stride 72

  const int tid = threadIdx.x;
  const int lane = tid & 63;
  const int lane15 = lane & 15;
  const int kg = (lane >> 4) << 3;        // k sub-offset in shorts (0,8,16,24)
  const int w = tid >> 6;                 // wave 0..7
  const int row0 = blockIdx.x * 32;
  const int rb = (lane >> 4) << 2;        // C/D row base within 16x16 tile

  // ---- hoisted GEMM1 B prefetch (depth 3), independent of xs ----
  const unsigned short* bp = w1p + (w * 32 + lane15) * 800 + kg;
  bf16x8 b0a = *(const bf16x8*)(bp);
  bf16x8 b0b = *(const bf16x8*)(bp + 16 * 800);
  bf16x8 b1a = *(const bf16x8*)(bp + 32);
  bf16x8 b1b = *(const bf16x8*)(bp + 16 * 800 + 32);
  bf16x8 b2a = *(const bf16x8*)(bp + 64);
  bf16x8 b2b = *(const bf16x8*)(bp + 16 * 800 + 64);

  // ---- hoisted GEMM2 FULL B prefetch (8 frags, 32 VGPR) ----
  // Used ~10 us from now; latency fully hidden under P0+GEMM1.
  const unsigned short* bp2 = w2b + (w * 16 + lane15) * 256 + kg;
  bf16x8 g2[8];
#pragma unroll
  for (int i = 0; i < 8; ++i) g2[i] = *(const bf16x8*)(bp2 + i * 32);

  // ---- Phase 0: x fp32 -> bf16 into xs ----
  {
    const float* xblk = x + (size_t)row0 * 784;
    for (int f = tid; f < 32 * 196; f += 512) {
      int rr = f / 196, c4 = f - rr * 196;
      float4 v = *(const float4*)(xblk + rr * 784 + (c4 << 2));
      unsigned int p0 = (unsigned)f2bf(v.x) | ((unsigned)f2bf(v.y) << 16);
      unsigned int p1 = (unsigned)f2bf(v.z) | ((unsigned)f2bf(v.w) << 16);
      unsigned int* dst = (unsigned int*)(xs + rr * 808 + (c4 << 2));
      dst[0] = p0;
      dst[1] = p1;
    }
    if (tid < 256) {  // zero-pad k = 784..799 (8 uints per row)
      int rr = tid >> 3, u = tid & 7;
      *(unsigned int*)(xs + rr * 808 + 784 + (u << 1)) = 0u;
    }
  }
  __syncthreads();

  // ---- GEMM1: [32][800] x w1p^T -> [32][256]; wave w owns cols w*32..+31 ----
  f32x4 acc1[2][2] = {};
  {
    const unsigned short* a0p = xs + lane15 * 808 + kg;
    const unsigned short* a1p = xs + (16 + lane15) * 808 + kg;
#pragma unroll
    for (int ks = 0; ks < 25; ++ks) {
      bf16x8 u0 = b0a, u1 = b0b;
      b0a = b1a; b0b = b1b;
      b1a = b2a; b1b = b2b;
      if (ks + 3 < 25) {
        b2a = *(const bf16x8*)(bp + (ks + 3) * 32);
        b2b = *(const bf16x8*)(bp + 16 * 800 + (ks + 3) * 32);
      }
      bf16x8 a0 = *(const bf16x8*)(a0p + ks * 32);
      bf16x8 a1 = *(const bf16x8*)(a1p + ks * 32);
      acc1[0][0] = mfma16(a0, u0, acc1[0][0]);
      acc1[1][0] = mfma16(a1, u0, acc1[1][0]);
      acc1[0][1] = mfma16(a0, u1, acc1[0][1]);
      acc1[1][1] = mfma16(a1, u1, acc1[1][1]);
    }
  }
  __syncthreads();  // all xs reads done before h1s overlays it

  // ---- epilogue1: +b1, relu -> h1s [32][264]; issue GEMM3 B prefetch ----
  const int mh = w >> 2, cq = w & 3;
  const unsigned short* bp3 = w3b + (cq * 16 + lane15) * 128 + kg;
  bf16x8 g3[4];
#pragma unroll
  for (int i = 0; i < 4; ++i) g3[i] = *(const bf16x8*)(bp3 + i * 32);
#pragma unroll
  for (int n = 0; n < 2; ++n) {
    const int col = w * 32 + n * 16 + lane15;
    const float bias = b1[col];
#pragma unroll
    for (int m = 0; m < 2; ++m) {
#pragma unroll
      for (int r = 0; r < 4; ++r) {
        float v = acc1[m][n][r] + bias;
        v = v > 0.f ? v : 0.f;
        h1s[(rb + m * 16 + r) * 264 + col] = f2bf(v);
      }
    }
  }
  __syncthreads();

  // ---- GEMM2: [32][256] x w2^T -> [32][128]; wave w owns cols w*16..+15 ----
  // B operand entirely in registers (g2, prefetched at kernel top).
  f32x4 acc2[2] = {};
  {
    const unsigned short* a0p = h1s + lane15 * 264 + kg;
    const unsigned short* a1p = h1s + (16 + lane15) * 264 + kg;
#pragma unroll
    for (int ks = 0; ks < 8; ++ks) {
      const int k0 = ks << 5;
      bf16x8 a0 = *(const bf16x8*)(a0p + k0);
      bf16x8 a1 = *(const bf16x8*)(a1p + k0);
      acc2[0] = mfma16(a0, g2[ks], acc2[0]);
      acc2[1] = mfma16(a1, g2[ks], acc2[1]);
    }
  }
  // epilogue2 -> h2s (disjoint region); issue GEMM4 B prefetch
  const unsigned short* bp4 = w4b + lane15 * 64 + kg;
  bf16x8 g4[2];
  g4[0] = *(const bf16x8*)(bp4);
  g4[1] = *(const bf16x8*)(bp4 + 32);
  {
    const int col = w * 16 + lane15;
    const float bias = b2[col];
#pragma unroll
    for (int m = 0; m < 2; ++m) {
#pragma unroll
      for (int r = 0; r < 4; ++r) {
        float v = acc2[m][r] + bias;
        v = v > 0.f ? v : 0.f;
        h2s[(rb + m * 16 + r) * 136 + col] = f2bf(v);
      }
    }
  }
  __syncthreads();

  // ---- GEMM3: [32][128] x w3^T -> [32][64]; wave (mh, cq); B in regs ----
  f32x4 acc3 = {};
  {
    const unsigned short* ap = h2s + (mh * 16 + lane15) * 136 + kg;
#pragma unroll
    for (int ks = 0; ks < 4; ++ks) {
      bf16x8 a0 = *(const bf16x8*)(ap + (ks << 5));
      acc3 = mfma16(a0, g3[ks], acc3);
    }
    // epilogue3 -> h3s (disjoint region)
    const int col = cq * 16 + lane15;
    const float bias = b3[col];
#pragma unroll
    for (int r = 0; r < 4; ++r) {
      float v = acc3[r] + bias;
      v = v > 0.f ? v : 0.f;
      h3s[(mh * 16 + rb + r) * 72 + col] = f2bf(v);
    }
  }
  __syncthreads();

  // ---- GEMM4: [32][64] x w4^T -> [32][10]; waves 0,1; B in regs ----
  if (w < 2) {
    f32x4 acc4 = {};
    const unsigned short* ap = h3s + (w * 16 + lane15) * 72 + kg;
#pragma unroll
    for (int ks = 0; ks < 2; ++ks) {
      bf16x8 a0 = *(const bf16x8*)(ap + (ks << 5));
      acc4 = mfma16(a0, g4[ks], acc4);
    }
    const int col = lane15;
    if (col < 10) {
      const float bias = b4[col];
#pragma unroll
      for (int r = 0; r < 4; ++r) {
        out[(size_t)(row0 + w * 16 + rb + r) * 10 + col] = acc4[r] + bias;
      }
    }
  }
}

extern "C" void kernel_launch(void* const* d_in, const int* in_sizes, int n_in,
                              void* d_out, int out_size, void* d_ws, size_t ws_size,
                              hipStream_t stream) {
  const float* x  = (const float*)d_in[0];
  const float* cw = (const float*)d_in[1];
  const float* w1 = (const float*)d_in[2];
  const float* b1 = (const float*)d_in[3];
  const float* w2 = (const float*)d_in[4];
  const float* b2 = (const float*)d_in[5];
  const float* w3 = (const float*)d_in[6];
  const float* b3 = (const float*)d_in[7];
  const float* w4 = (const float*)d_in[8];
  const float* b4 = (const float*)d_in[9];
  float* out = (float*)d_out;

  unsigned short* w1p = (unsigned short*)d_ws;          // 256*800
  unsigned short* w2b = w1p + 256 * 800;                // 128*256
  unsigned short* w3b = w2b + 128 * 256;                // 64*128
  unsigned short* w4b = w3b + 64 * 128;                 // 16*64

  hipLaunchKernelGGL(prep_weights, dim3(256), dim3(256), 0, stream,
                     w1, w2, w3, w4, cw, w1p, w2b, w3b, w4b);

  hipLaunchKernelGGL(fused_mlp, dim3(512), dim3(512), 0, stream,
                     x, w1p, w2b, w3b, w4b, b1, b2, b3, b4, out);
}